// Round 2
// baseline (2227.588 us; speedup 1.0000x reference)
//
#include <hip/hip_runtime.h>

#define NN 50000
#define NE 800000

// monotone float->uint transform so unsigned atomicMax == float max
__device__ __forceinline__ unsigned f2ord(float f) {
    unsigned u = __float_as_uint(f);
    return (u & 0x80000000u) ? ~u : (u | 0x80000000u);
}
__device__ __forceinline__ float ord2f(unsigned u) {
    return (u & 0x80000000u) ? __uint_as_float(u ^ 0x80000000u) : __uint_as_float(~u);
}

// One block per node, 320 threads (5 waves):
// waves 0-1: hs cols 0..127 (head0, head1)  -> hs[], als[] (shuffle reduce)
// waves 2-3: hd cols 0..127                 -> ald[] (shuffle reduce, hd not stored)
// wave 4   : lin cols 0..63                 -> lin[]
template <int DIN>
__global__ void __launch_bounds__(320)
node_gemm(const float* __restrict__ x,
          const float* __restrict__ Ws, const float* __restrict__ Wd,
          const float* __restrict__ Wl,
          const float* __restrict__ a_s, const float* __restrict__ a_d,
          float* __restrict__ hs, float* __restrict__ als,
          float* __restrict__ ald, float* __restrict__ lin)
{
    __shared__ float xs[DIN];
    const int n = blockIdx.x;
    const int t = threadIdx.x;
    if (t < DIN) xs[t] = x[n * DIN + t];
    __syncthreads();

    const float* W;
    int col, ldw;
    if (t < 128)      { W = Ws; col = t;       ldw = 128; }
    else if (t < 256) { W = Wd; col = t - 128; ldw = 128; }
    else              { W = Wl; col = t - 256; ldw = 64;  }

    float acc = 0.f;
#pragma unroll 8
    for (int k = 0; k < DIN; ++k)
        acc += xs[k] * W[k * ldw + col];

    if (t < 128) {
        hs[n * 128 + col] = acc;
        float v = acc * a_s[col];                  // col == h*64+c, a_s flat [2*64]
        for (int off = 32; off; off >>= 1) v += __shfl_xor(v, off, 64);
        if ((t & 63) == 0) als[n * 2 + (t >> 6)] = v;
    } else if (t < 256) {
        float v = acc * a_d[col];
        for (int off = 32; off; off >>= 1) v += __shfl_xor(v, off, 64);
        if ((t & 63) == 0) ald[n * 2 + ((t - 128) >> 6)] = v;
    } else {
        lin[n * 64 + col] = acc;
    }
}

__global__ void __launch_bounds__(256)
edge_scores(const int* __restrict__ ei,
            const float* __restrict__ als, const float* __restrict__ ald,
            float* __restrict__ ebuf, unsigned* __restrict__ mt)
{
    int e = blockIdx.x * 256 + threadIdx.x;
    if (e >= NE) return;
    int s = ei[e], d = ei[NE + e];
    float2 a = *(const float2*)&als[s * 2];
    float2 b = *(const float2*)&ald[d * 2];
    float e0 = a.x + b.x; e0 = (e0 >= 0.f) ? e0 : 0.2f * e0;
    float e1 = a.y + b.y; e1 = (e1 >= 0.f) ? e1 : 0.2f * e1;
    *(float2*)&ebuf[e * 2] = make_float2(e0, e1);
    atomicMax(&mt[d * 2 + 0], f2ord(e0));
    atomicMax(&mt[d * 2 + 1], f2ord(e1));
}

__global__ void __launch_bounds__(256)
edge_exp(const int* __restrict__ ei, float* __restrict__ ebuf,
         const unsigned* __restrict__ mt, float* __restrict__ den)
{
    int e = blockIdx.x * 256 + threadIdx.x;
    if (e >= NE) return;
    int d = ei[NE + e];
    float2 ev = *(const float2*)&ebuf[e * 2];
    float m0 = ord2f(mt[d * 2 + 0]);
    float m1 = ord2f(mt[d * 2 + 1]);
    float x0 = __expf(ev.x - m0);
    float x1 = __expf(ev.y - m1);
    *(float2*)&ebuf[e * 2] = make_float2(x0, x1);
    atomicAdd(&den[d * 2 + 0], x0);
    atomicAdd(&den[d * 2 + 1], x1);
}

// 128 threads per edge (j = h*64+c), 2 edges per 256-thread block
__global__ void __launch_bounds__(256)
edge_agg(const int* __restrict__ ei, const float* __restrict__ ebuf,
         const float* __restrict__ den, const float* __restrict__ hs,
         float* __restrict__ agg)
{
    long long gid = (long long)blockIdx.x * 256 + threadIdx.x;
    int e = (int)(gid >> 7);
    if (e >= NE) return;
    int j = (int)(gid & 127);
    int s = ei[e], d = ei[NE + e];
    int h = j >> 6;
    float alpha = ebuf[e * 2 + h] / (den[d * 2 + h] + 1e-16f);
    atomicAdd(&agg[d * 128 + j], hs[s * 128 + j] * alpha);
}

__global__ void __launch_bounds__(256)
node_finalize(const float* __restrict__ agg, const float* __restrict__ lin,
              const float* __restrict__ b, const float* __restrict__ bl,
              float* __restrict__ out)
{
    int i = blockIdx.x * 256 + threadIdx.x;
    if (i >= NN * 64) return;
    int n = i >> 6, c = i & 63;
    float v = 0.5f * (agg[n * 128 + c] + agg[n * 128 + 64 + c])
              + b[c] + lin[n * 64 + c] + bl[c];
    out[i] = fmaxf(v, 0.f);
}

extern "C" void kernel_launch(void* const* d_in, const int* in_sizes, int n_in,
                              void* d_out, int out_size, void* d_ws, size_t ws_size,
                              hipStream_t stream)
{
    const float* x  = (const float*)d_in[0];
    const int*   ei = (const int*)d_in[1];
    // per layer l: base = 2 + 7*l : Ws, Wd, as, ad, b, Wl, bl
    const float* Ws[3]; const float* Wd[3]; const float* As[3]; const float* Ad[3];
    const float* Bb[3]; const float* Wl[3]; const float* Bl[3];
    for (int l = 0; l < 3; ++l) {
        int base = 2 + 7 * l;
        Ws[l] = (const float*)d_in[base + 0];
        Wd[l] = (const float*)d_in[base + 1];
        As[l] = (const float*)d_in[base + 2];
        Ad[l] = (const float*)d_in[base + 3];
        Bb[l] = (const float*)d_in[base + 4];
        Wl[l] = (const float*)d_in[base + 5];
        Bl[l] = (const float*)d_in[base + 6];
    }

    float* ws   = (float*)d_ws;
    float* hs   = ws;                       // NN*128
    float* lin  = hs   + (size_t)NN * 128;  // NN*64
    float* als  = lin  + (size_t)NN * 64;   // NN*2
    float* ald  = als  + (size_t)NN * 2;    // NN*2
    float* ebuf = ald  + (size_t)NN * 2;    // NE*2
    unsigned* mt = (unsigned*)(ebuf + (size_t)NE * 2); // NN*2
    float* den  = (float*)mt + (size_t)NN * 2;         // NN*2
    float* agg  = den  + (size_t)NN * 2;    // NN*128
    float* h    = agg  + (size_t)NN * 128;  // NN*64 (reused across layers)

    const int EB  = (NE + 255) / 256;        // edge-parallel blocks
    const int AB  = (NE * 128 + 255) / 256;  // edge_agg blocks
    const int FB  = (NN * 64 + 255) / 256;   // finalize blocks

    for (int l = 0; l < 3; ++l) {
        hipMemsetAsync(mt,  0, sizeof(unsigned) * NN * 2, stream);
        hipMemsetAsync(den, 0, sizeof(float) * NN * 2, stream);
        hipMemsetAsync(agg, 0, sizeof(float) * NN * 128, stream);

        if (l == 0) {
            node_gemm<128><<<NN, 320, 0, stream>>>(
                x, Ws[0], Wd[0], Wl[0], As[0], Ad[0], hs, als, ald, lin);
        } else {
            node_gemm<64><<<NN, 320, 0, stream>>>(
                h, Ws[l], Wd[l], Wl[l], As[l], Ad[l], hs, als, ald, lin);
        }

        edge_scores<<<EB, 256, 0, stream>>>(ei, als, ald, ebuf, mt);
        edge_exp<<<EB, 256, 0, stream>>>(ei, ebuf, mt, den);
        edge_agg<<<AB, 256, 0, stream>>>(ei, ebuf, den, hs, agg);

        float* outp = (l == 2) ? (float*)d_out : h;
        node_finalize<<<FB, 256, 0, stream>>>(agg, lin, Bb[l], Bl[l], outp);
    }
}

// Round 4
// 1082.774 us; speedup vs baseline: 2.0573x; 2.0573x over previous
//
#include <hip/hip_runtime.h>

#define NN 50000
#define NE 800000

// ============================ CSR build (once per call) ============================

__global__ void __launch_bounds__(256)
hist_kernel(const int* __restrict__ ei, int* __restrict__ deg)
{
    int e = blockIdx.x * 256 + threadIdx.x;
    if (e >= NE) return;
    atomicAdd(&deg[ei[NE + e]], 1);
}

// single-block exclusive scan of deg[NN] -> row[NN+1]
__global__ void __launch_bounds__(1024)
scan_kernel(const int* __restrict__ deg, int* __restrict__ row)
{
    __shared__ int part[1024];
    const int T = 1024;
    const int C = (NN + T - 1) / T;
    int t = threadIdx.x;
    int s = t * C, e = min(s + C, NN);
    int sum = 0;
    for (int i = s; i < e; ++i) sum += deg[i];
    part[t] = sum;
    __syncthreads();
    for (int off = 1; off < T; off <<= 1) {
        int v = (t >= off) ? part[t - off] : 0;
        __syncthreads();
        part[t] += v;
        __syncthreads();
    }
    int run = (t == 0) ? 0 : part[t - 1];
    for (int i = s; i < e; ++i) { row[i] = run; run += deg[i]; }
    if (t == T - 1) row[NN] = run;
}

__global__ void __launch_bounds__(256)
cursor_init_kernel(const int* __restrict__ row, int* __restrict__ cursor)
{
    int i = blockIdx.x * 256 + threadIdx.x;
    if (i < NN) cursor[i] = row[i];
}

__global__ void __launch_bounds__(256)
scatter_kernel(const int* __restrict__ ei, int* __restrict__ cursor,
               int* __restrict__ csr_src)
{
    int e = blockIdx.x * 256 + threadIdx.x;
    if (e >= NE) return;
    int s = ei[e], d = ei[NE + e];
    int p = atomicAdd(&cursor[d], 1);
    csr_src[p] = s;
}

// ============================ per-layer kernels ============================

// Node GEMM: 16 nodes per block, 320 threads; thread t owns output column
// t<128: hs col (Ws), 128<=t<256: hd col (Wd, reduced to ald), t>=256: lin col (Wl).
template <int DIN>
__global__ void __launch_bounds__(320)
node_gemm(const float* __restrict__ x,
          const float* __restrict__ Ws, const float* __restrict__ Wd,
          const float* __restrict__ Wl,
          const float* __restrict__ a_s, const float* __restrict__ a_d,
          float* __restrict__ hs, float* __restrict__ als,
          float* __restrict__ ald, float* __restrict__ lin)
{
    const int TN = 16;
    __shared__ float xs[TN][DIN];
    __shared__ float red[TN][256];
    const int t = threadIdx.x;
    const int n0 = blockIdx.x * TN;

    for (int i = t; i < TN * DIN; i += 320)
        ((float*)xs)[i] = x[n0 * DIN + i];
    __syncthreads();

    const float* W; int col, ldw;
    if (t < 128)      { W = Ws; col = t;       ldw = 128; }
    else if (t < 256) { W = Wd; col = t - 128; ldw = 128; }
    else              { W = Wl; col = t - 256; ldw = 64;  }

    float acc[TN];
#pragma unroll
    for (int i = 0; i < TN; ++i) acc[i] = 0.f;

#pragma unroll 4
    for (int k = 0; k < DIN; ++k) {
        float w = W[k * ldw + col];
#pragma unroll
        for (int i = 0; i < TN; ++i) acc[i] += xs[i][k] * w;
    }

    if (t < 256) {
        float coef = (t < 128) ? a_s[col] : a_d[col];
#pragma unroll
        for (int i = 0; i < TN; ++i) red[i][t] = acc[i] * coef;
    }
    if (t < 128) {
#pragma unroll
        for (int i = 0; i < TN; ++i) hs[(size_t)(n0 + i) * 128 + col] = acc[i];
    } else if (t >= 256) {
#pragma unroll
        for (int i = 0; i < TN; ++i) lin[(size_t)(n0 + i) * 64 + col] = acc[i];
    }
    __syncthreads();

    if (t < 64) {
        int i = t >> 2, q = t & 3;
        const float* base = &red[i][q * 64];
        float sum = 0.f;
        for (int kk = 0; kk < 64; ++kk) sum += base[(kk + t) & 63];
        if (q < 2) als[(n0 + i) * 2 + q] = sum;
        else       ald[(n0 + i) * 2 + (q - 2)] = sum;
    }
}

// One wave per destination node. Scores computed in-place from als/ald (both
// wave-uniform per edge), exact segment max, then exp/den + coalesced hs gather.
// Fused head-mean + skip-linear + biases + relu. Zero atomics.
__global__ void __launch_bounds__(256)
gat_aggregate(const int* __restrict__ row, const int* __restrict__ csr_src,
              const float* __restrict__ als, const float* __restrict__ ald,
              const float* __restrict__ hs, const float* __restrict__ lin,
              const float* __restrict__ b, const float* __restrict__ bl,
              float* __restrict__ out)
{
    int w = (blockIdx.x * 256 + threadIdx.x) >> 6;   // node id = global wave id
    int j = threadIdx.x & 63;                        // channel
    if (w >= NN) return;
    int p0 = row[w], p1 = row[w + 1];
    float ad0 = ald[w * 2 + 0];
    float ad1 = ald[w * 2 + 1];

    // pass 1: exact max of leaky-relu scores per head (wave-uniform work)
    float m0 = -1e30f, m1 = -1e30f;
    for (int p = p0; p < p1; ++p) {
        int s = csr_src[p];
        float e0 = als[s * 2 + 0] + ad0; e0 = (e0 >= 0.f) ? e0 : 0.2f * e0;
        float e1 = als[s * 2 + 1] + ad1; e1 = (e1 >= 0.f) ? e1 : 0.2f * e1;
        m0 = fmaxf(m0, e0);
        m1 = fmaxf(m1, e1);
    }

    // pass 2: exp, denominator, weighted gather of hs
    float acc0 = 0.f, acc1 = 0.f, den0 = 0.f, den1 = 0.f;
    for (int p = p0; p < p1; ++p) {
        int s = csr_src[p];
        float e0 = als[s * 2 + 0] + ad0; e0 = (e0 >= 0.f) ? e0 : 0.2f * e0;
        float e1 = als[s * 2 + 1] + ad1; e1 = (e1 >= 0.f) ? e1 : 0.2f * e1;
        float a0 = __expf(e0 - m0);
        float a1 = __expf(e1 - m1);
        den0 += a0; den1 += a1;
        acc0 += a0 * hs[(size_t)s * 128 + j];
        acc1 += a1 * hs[(size_t)s * 128 + 64 + j];
    }

    float v = 0.5f * (acc0 / (den0 + 1e-16f) + acc1 / (den1 + 1e-16f))
            + b[j] + lin[(size_t)w * 64 + j] + bl[j];
    out[(size_t)w * 64 + j] = fmaxf(v, 0.f);
}

// ============================ launch ============================

extern "C" void kernel_launch(void* const* d_in, const int* in_sizes, int n_in,
                              void* d_out, int out_size, void* d_ws, size_t ws_size,
                              hipStream_t stream)
{
    const float* x  = (const float*)d_in[0];
    const int*   ei = (const int*)d_in[1];
    const float* Ws[3]; const float* Wd[3]; const float* As[3]; const float* Ad[3];
    const float* Bb[3]; const float* Wl[3]; const float* Bl[3];
    for (int l = 0; l < 3; ++l) {
        int base = 2 + 7 * l;
        Ws[l] = (const float*)d_in[base + 0];
        Wd[l] = (const float*)d_in[base + 1];
        As[l] = (const float*)d_in[base + 2];
        Ad[l] = (const float*)d_in[base + 3];
        Bb[l] = (const float*)d_in[base + 4];
        Wl[l] = (const float*)d_in[base + 5];
        Bl[l] = (const float*)d_in[base + 6];
    }

    float* ws = (float*)d_ws;
    float* hs    = ws;                          // NN*128
    float* lin   = hs  + (size_t)NN * 128;      // NN*64
    float* h     = lin + (size_t)NN * 64;       // NN*64
    float* als   = h   + (size_t)NN * 64;       // NN*2
    float* ald   = als + (size_t)NN * 2;        // NN*2
    int*   row     = (int*)(ald + (size_t)NN * 2); // NN+1
    int*   cursor  = row + (NN + 1);            // NN
    int*   deg     = cursor + NN;               // NN
    int*   csr_src = deg + NN;                  // NE

    const int EB  = (NE + 255) / 256;
    const int NB  = (NN + 255) / 256;
    const int AGB = (NN * 64 + 255) / 256;      // 1 wave per node, 4 waves/block

    // --- CSR build (edge structure is layer-invariant) ---
    hipMemsetAsync(deg, 0, sizeof(int) * NN, stream);
    hist_kernel<<<EB, 256, 0, stream>>>(ei, deg);
    scan_kernel<<<1, 1024, 0, stream>>>(deg, row);
    cursor_init_kernel<<<NB, 256, 0, stream>>>(row, cursor);
    scatter_kernel<<<EB, 256, 0, stream>>>(ei, cursor, csr_src);

    for (int l = 0; l < 3; ++l) {
        if (l == 0) {
            node_gemm<128><<<NN / 16, 320, 0, stream>>>(
                x, Ws[0], Wd[0], Wl[0], As[0], Ad[0], hs, als, ald, lin);
        } else {
            node_gemm<64><<<NN / 16, 320, 0, stream>>>(
                h, Ws[l], Wd[l], Wl[l], As[l], Ad[l], hs, als, ald, lin);
        }
        float* outp = (l == 2) ? (float*)d_out : h;
        gat_aggregate<<<AGB, 256, 0, stream>>>(row, csr_src, als, ald, hs, lin,
                                               Bb[l], Bl[l], outp);
    }
}

// Round 6
// 920.202 us; speedup vs baseline: 2.4208x; 1.1767x over previous
//
#include <hip/hip_runtime.h>
#include <hip/hip_bf16.h>

#define NN 50000
#define NE 800000

typedef __attribute__((ext_vector_type(8))) __bf16 bf16x8;
typedef __attribute__((ext_vector_type(4))) float float4v;

// ============================ CSR build (once per call) ============================

__global__ void __launch_bounds__(256)
hist_kernel(const int* __restrict__ ei, int* __restrict__ deg)
{
    int e = blockIdx.x * 256 + threadIdx.x;
    if (e >= NE) return;
    atomicAdd(&deg[ei[NE + e]], 1);
}

__global__ void __launch_bounds__(1024)
scan_kernel(const int* __restrict__ deg, int* __restrict__ row)
{
    __shared__ int part[1024];
    const int T = 1024;
    const int C = (NN + T - 1) / T;
    int t = threadIdx.x;
    int s = t * C, e = min(s + C, NN);
    int sum = 0;
    for (int i = s; i < e; ++i) sum += deg[i];
    part[t] = sum;
    __syncthreads();
    for (int off = 1; off < T; off <<= 1) {
        int v = (t >= off) ? part[t - off] : 0;
        __syncthreads();
        part[t] += v;
        __syncthreads();
    }
    int run = (t == 0) ? 0 : part[t - 1];
    for (int i = s; i < e; ++i) { row[i] = run; run += deg[i]; }
    if (t == T - 1) row[NN] = run;
}

__global__ void __launch_bounds__(256)
cursor_init_kernel(const int* __restrict__ row, int* __restrict__ cursor)
{
    int i = blockIdx.x * 256 + threadIdx.x;
    if (i < NN) cursor[i] = row[i];
}

__global__ void __launch_bounds__(256)
scatter_kernel(const int* __restrict__ ei, int* __restrict__ cursor,
               int* __restrict__ csr_src)
{
    int e = blockIdx.x * 256 + threadIdx.x;
    if (e >= NE) return;
    int s = ei[e], d = ei[NE + e];
    int p = atomicAdd(&cursor[d], 1);
    csr_src[p] = s;
}

// ============================ dtype prep ============================

__global__ void __launch_bounds__(256)
convert_x_kernel(const float* __restrict__ x, __bf16* __restrict__ xb, int n)
{
    int i = blockIdx.x * 256 + threadIdx.x;
    if (i < n) xb[i] = (__bf16)x[i];
}

// Wt[c][k], c in [0,320): c<128 -> Ws[k][c]; c<256 -> Wd[k][c-128]; else Wl[k][c-256]
template <int K>
__global__ void __launch_bounds__(256)
convert_w_kernel(const float* __restrict__ Ws, const float* __restrict__ Wd,
                 const float* __restrict__ Wl, __bf16* __restrict__ Wt)
{
    int i = blockIdx.x * 256 + threadIdx.x;
    if (i >= 320 * K) return;
    int c = i / K, k = i % K;
    float v;
    if (c < 128)      v = Ws[k * 128 + c];
    else if (c < 256) v = Wd[k * 128 + (c - 128)];
    else              v = Wl[k * 64 + (c - 256)];
    Wt[i] = (__bf16)v;
}

// ============================ MFMA node GEMM ============================
// C[50000 x 320] = X[50000 x K] @ W[K x 320], W pre-transposed to Wt[320][K].
// 256 threads = 4 waves; wave w owns 16 nodes, all 20 col-tiles of 16.
// A frag: X[m=lane&15][k=quad*8+j]; B frag: Wt[n=lane&15][k=quad*8+j];
// C/D: col=lane&15, row=quad*4+reg (AMD matrix-core layout, m89/m120-verified).
// Tiles 0..7 -> hs (fp32), 8..15 -> hd (bf16), 16..19 -> lin (fp32).
template <int K>
__global__ void __launch_bounds__(256)
mfma_gemm(const __bf16* __restrict__ xb, const __bf16* __restrict__ Wt,
          float* __restrict__ hs, __bf16* __restrict__ hd,
          float* __restrict__ lin)
{
    const int wave = threadIdx.x >> 6;
    const int lane = threadIdx.x & 63;
    const int l15 = lane & 15, quad = lane >> 4;
    const int n0 = blockIdx.x * 64 + wave * 16;
    const int nA = min(n0 + l15, NN - 1);          // clamp OOB rows (stores guarded)

    float4v acc[20];
#pragma unroll
    for (int t = 0; t < 20; ++t) acc[t] = (float4v){0.f, 0.f, 0.f, 0.f};

#pragma unroll
    for (int ks = 0; ks < K / 32; ++ks) {
        bf16x8 af = *(const bf16x8*)(xb + (size_t)nA * K + ks * 32 + quad * 8);
#pragma unroll
        for (int t = 0; t < 20; ++t) {
            bf16x8 bf = *(const bf16x8*)(Wt + (size_t)(t * 16 + l15) * K + ks * 32 + quad * 8);
            acc[t] = __builtin_amdgcn_mfma_f32_16x16x32_bf16(af, bf, acc[t], 0, 0, 0);
        }
    }

#pragma unroll
    for (int t = 0; t < 8; ++t) {
        int col = t * 16 + l15;
#pragma unroll
        for (int r = 0; r < 4; ++r) {
            int n = n0 + quad * 4 + r;
            if (n < NN) hs[(size_t)n * 128 + col] = acc[t][r];
        }
    }
#pragma unroll
    for (int t = 8; t < 16; ++t) {
        int col = (t - 8) * 16 + l15;
#pragma unroll
        for (int r = 0; r < 4; ++r) {
            int n = n0 + quad * 4 + r;
            if (n < NN) hd[(size_t)n * 128 + col] = (__bf16)acc[t][r];
        }
    }
#pragma unroll
    for (int t = 16; t < 20; ++t) {
        int col = (t - 16) * 16 + l15;
#pragma unroll
        for (int r = 0; r < 4; ++r) {
            int n = n0 + quad * 4 + r;
            if (n < NN) lin[(size_t)n * 64 + col] = acc[t][r];
        }
    }
}

// als/ald from stored hs/hd: one wave per node, full-width-64 butterfly.
__global__ void __launch_bounds__(256)
reduce_al_kernel(const float* __restrict__ hs, const __bf16* __restrict__ hd,
                 const float* __restrict__ a_s, const float* __restrict__ a_d,
                 float* __restrict__ als, float* __restrict__ ald)
{
    int n = (blockIdx.x * 256 + threadIdx.x) >> 6;
    int j = threadIdx.x & 63;
    if (n >= NN) return;
    float s0 = hs[(size_t)n * 128 + j]       * a_s[j];
    float s1 = hs[(size_t)n * 128 + 64 + j]  * a_s[64 + j];
    float d0 = (float)hd[(size_t)n * 128 + j]      * a_d[j];
    float d1 = (float)hd[(size_t)n * 128 + 64 + j] * a_d[64 + j];
    for (int m = 32; m; m >>= 1) {
        s0 += __shfl_xor(s0, m);
        s1 += __shfl_xor(s1, m);
        d0 += __shfl_xor(d0, m);
        d1 += __shfl_xor(d1, m);
    }
    if (j == 0) {
        als[n * 2 + 0] = s0;
        als[n * 2 + 1] = s1;
        ald[n * 2 + 0] = d0;
        ald[n * 2 + 1] = d1;
    }
}

// ============================ fused aggregate ============================

__device__ __forceinline__ void store_o(float* p, float v) { *p = v; }
__device__ __forceinline__ void store_o(__bf16* p, float v) { *p = (__bf16)v; }

// One wave per destination node; zero atomics.  (R4-verified structure.)
template <typename TO>
__global__ void __launch_bounds__(256)
gat_aggregate(const int* __restrict__ row, const int* __restrict__ csr_src,
              const float* __restrict__ als, const float* __restrict__ ald,
              const float* __restrict__ hs, const float* __restrict__ lin,
              const float* __restrict__ b, const float* __restrict__ bl,
              TO* __restrict__ out)
{
    int w = (blockIdx.x * 256 + threadIdx.x) >> 6;   // node id = global wave id
    int j = threadIdx.x & 63;                        // channel
    if (w >= NN) return;
    int p0 = row[w], p1 = row[w + 1];
    float ad0 = ald[w * 2 + 0];
    float ad1 = ald[w * 2 + 1];

    float m0 = -1e30f, m1 = -1e30f;
    for (int p = p0; p < p1; ++p) {
        int s = csr_src[p];
        float e0 = als[s * 2 + 0] + ad0; e0 = (e0 >= 0.f) ? e0 : 0.2f * e0;
        float e1 = als[s * 2 + 1] + ad1; e1 = (e1 >= 0.f) ? e1 : 0.2f * e1;
        m0 = fmaxf(m0, e0);
        m1 = fmaxf(m1, e1);
    }

    float acc0 = 0.f, acc1 = 0.f, den0 = 0.f, den1 = 0.f;
    for (int p = p0; p < p1; ++p) {
        int s = csr_src[p];
        float e0 = als[s * 2 + 0] + ad0; e0 = (e0 >= 0.f) ? e0 : 0.2f * e0;
        float e1 = als[s * 2 + 1] + ad1; e1 = (e1 >= 0.f) ? e1 : 0.2f * e1;
        float a0 = __expf(e0 - m0);
        float a1 = __expf(e1 - m1);
        den0 += a0; den1 += a1;
        acc0 += a0 * hs[(size_t)s * 128 + j];
        acc1 += a1 * hs[(size_t)s * 128 + 64 + j];
    }

    float v = 0.5f * (acc0 / (den0 + 1e-16f) + acc1 / (den1 + 1e-16f))
            + b[j] + lin[(size_t)w * 64 + j] + bl[j];
    store_o(&out[(size_t)w * 64 + j], fmaxf(v, 0.f));
}

// ============================ launch ============================

extern "C" void kernel_launch(void* const* d_in, const int* in_sizes, int n_in,
                              void* d_out, int out_size, void* d_ws, size_t ws_size,
                              hipStream_t stream)
{
    const float* x  = (const float*)d_in[0];
    const int*   ei = (const int*)d_in[1];
    const float* Ws[3]; const float* Wd[3]; const float* As[3]; const float* Ad[3];
    const float* Bb[3]; const float* Wl[3]; const float* Bl[3];
    for (int l = 0; l < 3; ++l) {
        int base = 2 + 7 * l;
        Ws[l] = (const float*)d_in[base + 0];
        Wd[l] = (const float*)d_in[base + 1];
        As[l] = (const float*)d_in[base + 2];
        Ad[l] = (const float*)d_in[base + 3];
        Bb[l] = (const float*)d_in[base + 4];
        Wl[l] = (const float*)d_in[base + 5];
        Bl[l] = (const float*)d_in[base + 6];
    }

    float* ws = (float*)d_ws;
    float* hs   = ws;                           // NN*128 f32
    float* lin  = hs  + (size_t)NN * 128;       // NN*64 f32
    float* als  = lin + (size_t)NN * 64;        // NN*2
    float* ald  = als + (size_t)NN * 2;         // NN*2
    __bf16* hd  = (__bf16*)(ald + (size_t)NN * 2);  // NN*128 bf16
    __bf16* xb  = hd + (size_t)NN * 128;            // NN*128 bf16
    __bf16* hb  = xb + (size_t)NN * 128;            // NN*64 bf16
    __bf16* Wt1 = hb + (size_t)NN * 64;             // 320*128
    __bf16* Wt2 = Wt1 + 320 * 128;                  // 320*64
    __bf16* Wt3 = Wt2 + 320 * 64;                   // 320*64
    int* row     = (int*)(Wt3 + 320 * 64);      // NN+1
    int* cursor  = row + (NN + 1);              // NN
    int* deg     = cursor + NN;                 // NN
    int* csr_src = deg + NN;                    // NE

    const int EB  = (NE + 255) / 256;
    const int NB  = (NN + 255) / 256;
    const int WB  = (NN * 64 + 255) / 256;      // 1 wave per node kernels
    const int GB  = (NN + 63) / 64;             // mfma_gemm blocks (64 nodes each)

    // --- CSR build ---
    hipMemsetAsync(deg, 0, sizeof(int) * NN, stream);
    hist_kernel<<<EB, 256, 0, stream>>>(ei, deg);
    scan_kernel<<<1, 1024, 0, stream>>>(deg, row);
    cursor_init_kernel<<<NB, 256, 0, stream>>>(row, cursor);
    scatter_kernel<<<EB, 256, 0, stream>>>(ei, cursor, csr_src);

    // --- dtype prep ---
    convert_x_kernel<<<(NN * 128 + 255) / 256, 256, 0, stream>>>(x, xb, NN * 128);
    convert_w_kernel<128><<<(320 * 128 + 255) / 256, 256, 0, stream>>>(Ws[0], Wd[0], Wl[0], Wt1);
    convert_w_kernel<64><<<(320 * 64 + 255) / 256, 256, 0, stream>>>(Ws[1], Wd[1], Wl[1], Wt2);
    convert_w_kernel<64><<<(320 * 64 + 255) / 256, 256, 0, stream>>>(Ws[2], Wd[2], Wl[2], Wt3);

    for (int l = 0; l < 3; ++l) {
        if (l == 0) {
            mfma_gemm<128><<<GB, 256, 0, stream>>>(xb, Wt1, hs, hd, lin);
        } else {
            const __bf16* wt = (l == 1) ? Wt2 : Wt3;
            mfma_gemm<64><<<GB, 256, 0, stream>>>(hb, wt, hs, hd, lin);
        }
        reduce_al_kernel<<<WB, 256, 0, stream>>>(hs, hd, As[l], Ad[l], als, ald);
        if (l == 2) {
            gat_aggregate<float><<<WB, 256, 0, stream>>>(
                row, csr_src, als, ald, hs, lin, Bb[l], Bl[l], (float*)d_out);
        } else {
            gat_aggregate<__bf16><<<WB, 256, 0, stream>>>(
                row, csr_src, als, ald, hs, lin, Bb[l], Bl[l], hb);
        }
    }
}